// Round 15
// baseline (156.069 us; speedup 1.0000x reference)
//
#include <hip/hip_runtime.h>
#include <hip/hip_bf16.h>

#define B_ 4
#define C_ 512
#define T_ 1024
#define SCALE_ 0.125f
#define EPS_ 1e-5f

typedef unsigned short u16;
typedef __attribute__((ext_vector_type(8))) unsigned short u16x8;
typedef __attribute__((ext_vector_type(4))) unsigned short u16x4;
typedef __attribute__((ext_vector_type(8))) short s16x8;
typedef __attribute__((ext_vector_type(4))) float f32x4;

// ws byte offsets (ws is 256 MiB)
#define QT_OFF    (0x0ull)         // bf16 Qt[B][T][C]   4 MB (Q pre-scaled by 1/8)
#define KS_OFF    (0x400000ull)    // bf16 KS swizzled [B][t32][half][f][lane][8] 4 MB
#define VS_OFF    (0x800000ull)    // bf16 VS swizzled [B][g][t32][dj][lane][8]   4 MB
#define XT_OFF    (0xC00000ull)    // bf16 Xt[B][T][C]   4 MB
#define WB_OFF    (0x1480000ull)   // bf16 W[4][512][512]: wq,wk,wv,wp  2 MB
#define LP_OFF    (0x1680000ull)   // fp32 lpart [2][32][1024] 256 KB
#define L2P_OFF   (0x1700000ull)   // fp32 l2part[2][32][1024] 256 KB
#define WS_OFF    (0x1780000ull)   // fp32 ws[512][64] 128 KB
#define VSUM_OFF  (0x17A0000ull)   // fp32 vsum[B][8][64] 8 KB
#define OP_OFF    (0x2000000ull)   // fp32 Opart[2][32][1024][64] 16 MB

static __device__ __forceinline__ u16 f2bf(float f) {
  unsigned u = __float_as_uint(f);
  unsigned r = (u + 0x7fff + ((u >> 16) & 1)) >> 16;  // RNE
  return (u16)r;
}
static __device__ __forceinline__ float b2f(u16 x) {
  return __uint_as_float(((unsigned)x) << 16);
}
static __device__ __forceinline__ f32x4 mfma16(s16x8 a, s16x8 b, f32x4 c) {
  return __builtin_amdgcn_mfma_f32_16x16x32_bf16(a, b, c, 0, 0, 0);
}
// lgkmcnt(0) + raw barrier: LDS ops ordered, but in-flight GLOBAL loads (to
// regs) legitimately cross the barrier -- the T3/T14 pipeline primitive.
#define BARSYNC()                                       \
  {                                                     \
    asm volatile("s_waitcnt lgkmcnt(0)" ::: "memory");  \
    __builtin_amdgcn_s_barrier();                       \
  }

// ---- prep: blocks [0,512) wcvt; [512,640) wsum+vsum-zero; [640,1152)
// transpose x -> Xt[b][t][c] bf16. Branch is block-uniform. ----
__global__ __launch_bounds__(256) void prep_k(
    const float* __restrict__ x, const float* __restrict__ wq,
    const float* __restrict__ wk, const float* __restrict__ wv,
    const float* __restrict__ wp, u16* __restrict__ wb,
    float* __restrict__ ws, float* __restrict__ vsum, u16* __restrict__ xt) {
  const int id = blockIdx.x;
  const int tid = threadIdx.x;
  __shared__ float Ts[64][65];
  if (id < 512) {  // ---- wcvt: fp32 -> bf16, 4 weight matrices ----
    const int i = (id << 8) + tid;
    const int idx = i << 3;
    const int which = idx >> 18;  // uniform per block
    const int off = idx & 262143;
    const float* s = which == 0 ? wq : which == 1 ? wk : which == 2 ? wv : wp;
    const float4 f0 = *(const float4*)(s + off);
    const float4 f1 = *(const float4*)(s + off + 4);
    u16x8 o;
    o[0] = f2bf(f0.x); o[1] = f2bf(f0.y); o[2] = f2bf(f0.z); o[3] = f2bf(f0.w);
    o[4] = f2bf(f1.x); o[5] = f2bf(f1.y); o[6] = f2bf(f1.z); o[7] = f2bf(f1.w);
    *(u16x8*)(wb + idx) = o;
  } else if (id < 640) {  // ---- ws[o][d] = sum_j wp[o][j*64+d]; zero vsum ----
    const int idx = ((id - 512) << 8) + tid;
    if (id - 512 < 8) vsum[idx] = 0.f;
    const int o = idx >> 6, d = idx & 63;
    float s = 0.f;
#pragma unroll
    for (int j = 0; j < 8; ++j) s += wp[(o << 9) + (j << 6) + d];
    ws[idx] = s;
  } else {  // ---- transpose x[b][c][t] -> Xt[b][t][c] bf16 ----
    const int id3 = id - 640;
    const int b = id3 >> 7, rem = id3 & 127;
    const int t0 = (rem & 15) << 6;
    const int c0 = (rem >> 4) << 6;
    const float* __restrict__ X = x + (size_t)b * (C_ * (size_t)T_);
    u16* __restrict__ Xt = xt + (size_t)b * (T_ * (size_t)C_);
#pragma unroll
    for (int i = 0; i < 4; ++i) {
      const int e = tid + (i << 8);
      const int r = e >> 4, c4 = e & 15;
      const float4 v =
          *(const float4*)(X + (size_t)(c0 + r) * T_ + t0 + (c4 << 2));
      Ts[r][(c4 << 2) + 0] = v.x; Ts[r][(c4 << 2) + 1] = v.y;
      Ts[r][(c4 << 2) + 2] = v.z; Ts[r][(c4 << 2) + 3] = v.w;
    }
    __syncthreads();
#pragma unroll
    for (int i = 0; i < 2; ++i) {
      const int e = tid + (i << 8);
      const int tt = e >> 3, c8 = e & 7;
      u16x8 o;
#pragma unroll
      for (int j = 0; j < 8; ++j) o[j] = f2bf(Ts[(c8 << 3) + j][tt]);
      *(u16x8*)(Xt + (size_t)(t0 + tt) * C_ + c0 + (c8 << 3)) = o;
    }
  }
}

// ---- unified QKV GEMM, 128x64 tiles, 768 blocks (3/CU), DEPTH-2 REGISTER
// PREFETCH (ping-pong reg sets, loop body doubled for static indexing).
// Q epilogue through LDS -> coalesced u16x8 stores. ----
__global__ __launch_bounds__(256) void gemm_qkv(
    const u16* __restrict__ xt, const u16* __restrict__ wqb,
    const u16* __restrict__ wkb, const u16* __restrict__ wvb,
    u16* __restrict__ qto, u16* __restrict__ ks, u16* __restrict__ vs,
    float* __restrict__ vsum) {
  const int z = blockIdx.z;
  const int tid = threadIdx.x;
  const int w = tid >> 6, lane = tid & 63, lr = lane & 15, lq = lane >> 4;
  const int wm = (w >> 1) << 6, wn = (w & 1) << 5;  // 2x2 waves: 64m x 32n
  __shared__ __align__(16) u16 As[128][72];
  __shared__ __align__(16) u16 Bs[64][72];
  u16* Ts = &As[0][0];  // epilogue staging tile [128][72] (aliases As)
  const u16 *Ag, *Bg;
  int m0, n0, mode, b;
  if (z < 8) {
    const int which = z >> 2;
    b = z & 3;
    Ag = xt + (size_t)b * (T_ * (size_t)C_);
    m0 = blockIdx.x << 7;  // t: 8 tiles
    Bg = which ? wkb : wqb;
    n0 = blockIdx.y << 6;  // o: 8 tiles
    mode = which;          // 0 = Q, 1 = K
  } else {
    b = z - 8;
    const int ti = (blockIdx.y << 3) | blockIdx.x;  // [0,64)
    Ag = wvb;
    m0 = (ti >> 4) << 7;  // o: 4 tiles
    Bg = xt + (size_t)b * (T_ * (size_t)C_);
    n0 = (ti & 15) << 6;  // t: 16 tiles
    mode = 2;
  }
  u16x8 rA0[4], rB0[2], rA1[4], rB1[2];
#define LOADQ(RA, RB, K)                                                  \
  {                                                                       \
    _Pragma("unroll") for (int it = 0; it < 4; ++it) {                    \
      const int e = tid + (it << 8);                                      \
      const int r = e >> 3, c8 = (e & 7) << 3;                            \
      RA[it] = *(const u16x8*)(Ag + (size_t)(m0 + r) * C_ + (K) + c8);    \
    }                                                                     \
    _Pragma("unroll") for (int it = 0; it < 2; ++it) {                    \
      const int e = tid + (it << 8);                                      \
      const int r = e >> 3, c8 = (e & 7) << 3;                            \
      RB[it] = *(const u16x8*)(Bg + (size_t)(n0 + r) * C_ + (K) + c8);    \
    }                                                                     \
  }
#define WRITEQ(RA, RB)                                       \
  {                                                          \
    _Pragma("unroll") for (int it = 0; it < 4; ++it) {       \
      const int e = tid + (it << 8);                         \
      *(u16x8*)&As[e >> 3][(e & 7) << 3] = RA[it];           \
    }                                                        \
    _Pragma("unroll") for (int it = 0; it < 2; ++it) {       \
      const int e = tid + (it << 8);                         \
      *(u16x8*)&Bs[e >> 3][(e & 7) << 3] = RB[it];           \
    }                                                        \
  }
#define MFMAQ()                                                                \
  {                                                                            \
    _Pragma("unroll") for (int kf = 0; kf < 2; ++kf) {                         \
      const int ko = (kf << 5) + (lq << 3);                                    \
      s16x8 a[4], bb[2];                                                       \
      _Pragma("unroll") for (int i = 0; i < 4; ++i) a[i] =                     \
          *(const s16x8*)&As[wm + (i << 4) + lr][ko];                          \
      _Pragma("unroll") for (int j = 0; j < 2; ++j) bb[j] =                    \
          *(const s16x8*)&Bs[wn + (j << 4) + lr][ko];                          \
      _Pragma("unroll") for (int i = 0; i < 4; ++i)                            \
          _Pragma("unroll") for (int j = 0; j < 2; ++j) acc[i][j] =            \
              mfma16(a[i], bb[j], acc[i][j]);                                  \
    }                                                                          \
  }
  f32x4 acc[4][2] = {};
  LOADQ(rA0, rB0, 0);
  LOADQ(rA1, rB1, 64);
  for (int k0 = 0; k0 < C_; k0 += 128) {
    // even K-step (k0)
    if (k0) BARSYNC();  // prev reads consumed (all waves)
    WRITEQ(rA0, rB0);
    if (k0 + 128 < C_) LOADQ(rA0, rB0, k0 + 128);  // 2 phases of cover
    BARSYNC();  // writes committed
    MFMAQ();
    // odd K-step (k0+64)
    BARSYNC();
    WRITEQ(rA1, rB1);
    if (k0 + 192 < C_) LOADQ(rA1, rB1, k0 + 192);
    BARSYNC();
    MFMAQ();
  }
#undef LOADQ
#undef WRITEQ
#undef MFMAQ
  if (mode == 2) {
    // ---- vsum contribution: sum over this tile's 64 t-cols, atomic ----
#pragma unroll
    for (int i = 0; i < 4; ++i)
#pragma unroll
      for (int r = 0; r < 4; ++r) {
        float s = acc[i][0][r] + acc[i][1][r];
        s += __shfl_xor(s, 1, 64);
        s += __shfl_xor(s, 2, 64);
        s += __shfl_xor(s, 4, 64);
        s += __shfl_xor(s, 8, 64);
        if (lr == 0) {
          const int o = m0 + wm + (i << 4) + (lq << 2) + r;
          atomicAdd(&vsum[(((b << 3) | (o >> 6)) << 6) | (o & 63)], s);
        }
      }
  }
  BARSYNC();  // all waves done reading As before Ts overwrite
  // ---- stage output tile [m_local 128][n_local 64] (stride 72) in LDS ----
  const float osc = (mode == 0) ? SCALE_ : 1.0f;
#pragma unroll
  for (int i = 0; i < 4; ++i)
#pragma unroll
    for (int j = 0; j < 2; ++j)
#pragma unroll
      for (int r = 0; r < 4; ++r)
        Ts[(wm + (i << 4) + (lq << 2) + r) * 72 + wn + (j << 4) + lr] =
            f2bf(acc[i][j][r] * osc);
  __syncthreads();
  if (mode == 0) {
    // coalesced Qt store: row = tid>>1, col-half = (tid&1)*32; 4 u16x8 each
    u16* Y = qto + (size_t)b * (T_ * (size_t)C_);
    const int row = tid >> 1, ch32 = (tid & 1) << 5;
    u16* dst = Y + (size_t)(m0 + row) * C_ + n0 + ch32;
    const u16* src = &Ts[row * 72 + ch32];
#pragma unroll
    for (int u = 0; u < 4; ++u)
      *(u16x8*)(dst + (u << 3)) = *(const u16x8*)(src + (u << 3));
    return;
  }
  const int ch = tid >> 4, part = tid & 15;  // 16 chunks x 16 threads
  if (mode == 1) {
    // chunk = (t32l[4], half[2], fl[2]); lanek = u*16+part -> coalesced
    const int t32l = ch >> 2, half = (ch >> 1) & 1, fl = ch & 1;
    const int t32g = (m0 >> 5) + t32l, fg = (n0 >> 5) + fl;
    u16* dst =
        ks + (((((size_t)((b << 5) | t32g) << 1) | half) << 4 | fg) << 9);
#pragma unroll
    for (int u = 0; u < 4; ++u) {
      const int lanek = (u << 4) + part;
      const int quadk = lanek >> 4, lrk = lanek & 15;
      const int rr = ((lrk >> 2) << 3) | (half << 2) | (lrk & 3);
      const u16x8 v =
          *(const u16x8*)&Ts[((t32l << 5) + rr) * 72 + (fl << 5) + (quadk << 3)];
      *(u16x8*)(dst + (lanek << 3)) = v;
    }
  } else {
    // chunk = (gl[2], t32l[2], dj[4]); lanev = u*16+part -> coalesced
    const int gl = ch >> 3, t32l = (ch >> 2) & 1, dj = ch & 3;
    const int gg = (m0 >> 6) + gl, t32g = (n0 >> 5) + t32l;
    u16* dst =
        vs + (((((size_t)((b << 3) | gg) << 5) | t32g) << 2 | dj) << 9);
#pragma unroll
    for (int u = 0; u < 4; ++u) {
      const int lanev = (u << 4) + part;
      const int quadv = lanev >> 4, lrv = lanev & 15;
      const u16x8 v = *(const u16x8*)&Ts[((gl << 6) + (dj << 4) + lrv) * 72 +
                                         (t32l << 5) + (quadv << 3)];
      *(u16x8*)(dst + (lanev << 3)) = v;
    }
  }
}

// ---- FUSED attention: R14 structure + T14 V-PREFETCH: PV's 16 V frags
// were loaded AFTER the P-ready barrier and consumed immediately (exposed
// L2 latency x4 chunks). Now: 8 frags issued BEFORE the barrier (latency
// hides under barrier + other waves' QK tails), 8 right after, all PV
// MFMAs read registers. Barriers are lgkmcnt-only raw s_barrier so the
// in-flight V loads cross legally. VGPR 56 -> ~120 (128 budget). ----
__global__ __launch_bounds__(512, 4) void attn_fused(
    const u16* __restrict__ Qt, const u16* __restrict__ KS,
    const u16* __restrict__ VS, const float* __restrict__ wh,
    float* __restrict__ Opart, float* __restrict__ lpart,
    float* __restrict__ l2part) {
  const int id = blockIdx.x;
  const int xcd = id & 7;
  const int b = xcd >> 1;
  const int hi = id >> 3;                       // [0,64)
  const int qb = ((xcd & 1) << 5) | (hi & 31);  // [0,64)
  const int tq = hi >> 5;                       // [0,2) t-half
  const int q0 = qb << 4;
  const int tid = threadIdx.x;
  const int w = tid >> 6, lane = tid & 63;
  const int lr = lane & 15, quad = lane >> 4;

  __shared__ __align__(16) u16 Qs[16][522];       // 16704 B
  __shared__ __align__(16) u16 Plds[8][16][136];  // 34816 B
  float* Sbuf = (float*)&Plds[0][0][0];  // epilogue alias (Plds dead by then)

  {  // stage Q tile (16 x 512)
    const u16* Qb = Qt + ((size_t)b * T_ + q0) * C_;
    for (int i = tid; i < 1024; i += 512) {
      const int r = i >> 6, c8 = i & 63;
      *(u16x8*)&Qs[r][c8 << 3] = *(const u16x8*)(Qb + (size_t)r * C_ + (c8 << 3));
    }
  }

  const u16* __restrict__ Qrow = &Qs[lr][quad << 3];
  const int g = w;  // PV head owned by this wave
  const int win = w >> 1, half = w & 1;  // QK: window pair, K-half
  const u16* __restrict__ Vc =
      VS + (((size_t)((b << 3) | g)) << 16) + (lane << 3);

  float lacc[8] = {}, l2acc[8] = {};
  f32x4 acc[4] = {};

  __syncthreads();

  for (int c = 0; c < 4; ++c) {
    // ---- QK + mix + exp: K loads lane-contiguous from KS ----
    const int t32k = (tq << 4) + (c << 2) + win;
    const u16* __restrict__ Kc =
        KS + (((size_t)((((b << 5) | t32k) << 1) | half)) << 13) + (lane << 3);
    f32x4 m[8] = {};
#pragma unroll 4
    for (int h = 0; h < 8; ++h) {
      f32x4 a0 = {0.f, 0.f, 0.f, 0.f};
      const s16x8 qf0 = *(const s16x8*)(Qrow + (h << 6));
      const s16x8 k0 = *(const s16x8*)(Kc + (h << 10));
      a0 = mfma16(k0, qf0, a0);
      const s16x8 qf1 = *(const s16x8*)(Qrow + (h << 6) + 32);
      const s16x8 k1 = *(const s16x8*)(Kc + (h << 10) + 512);
      a0 = mfma16(k1, qf1, a0);
#pragma unroll
      for (int gg = 0; gg < 8; ++gg) {
        const float wgh = wh[(gg << 3) + h];  // uniform -> SGPR
        m[gg] += a0 * wgh;
      }
    }
    // lane's t slots: win*32 + quad*8 + half*4 + {0..3}; q = lr
#pragma unroll
    for (int gg = 0; gg < 8; ++gg) {
      f32x4 e0;
#pragma unroll
      for (int k = 0; k < 4; ++k) e0[k] = __expf(m[gg][k]);
      u16x4 o;
#pragma unroll
      for (int k = 0; k < 4; ++k) o[k] = f2bf(e0[k]);
      *(u16x4*)&Plds[gg][lr][(win << 5) + (quad << 3) + (half << 2)] = o;
      lacc[gg] += e0[0] + e0[1] + e0[2] + e0[3];
      l2acc[gg] += e0[0] * e0[0] + e0[1] * e0[1] + e0[2] * e0[2] + e0[3] * e0[3];
    }
    // ---- T14: issue first half of V loads BEFORE the P-ready barrier ----
    s16x8 vA[8], vB[8];
#pragma unroll
    for (int tw = 0; tw < 2; ++tw)
#pragma unroll
      for (int dj = 0; dj < 4; ++dj)
        vA[(tw << 2) + dj] = *(const s16x8*)(
            Vc + ((size_t)((tq << 4) + (c << 2) + tw) << 11) + (dj << 9));
    BARSYNC();  // P ready (lgkm only -- V loads stay in flight)
#pragma unroll
    for (int tw = 2; tw < 4; ++tw)
#pragma unroll
      for (int dj = 0; dj < 4; ++dj)
        vB[((tw - 2) << 2) + dj] = *(const s16x8*)(
            Vc + ((size_t)((tq << 4) + (c << 2) + tw) << 11) + (dj << 9));
    // ---- PV: all operands in registers ----
#pragma unroll
    for (int tw = 0; tw < 4; ++tw) {
      const s16x8 pa = *(const s16x8*)&Plds[g][lr][(tw << 5) + (quad << 3)];
#pragma unroll
      for (int dj = 0; dj < 4; ++dj) {
        const s16x8 vb =
            (tw < 2) ? vA[(tw << 2) + dj] : vB[((tw - 2) << 2) + dj];
        acc[dj] = mfma16(pa, vb, acc[dj]);
      }
    }
    BARSYNC();  // P consumed (ds_reads drained), safe to overwrite
  }

  // ---- write raw f32 partial O (normalization happens in gemm_proj) ----
  const int bg = (b << 3) + g;
  const size_t obase = ((((size_t)(tq << 5) + bg) << 10) + q0) * 64;
#pragma unroll
  for (int dj = 0; dj < 4; ++dj) {
    const int d = (dj << 4) + lr;
#pragma unroll
    for (int r = 0; r < 4; ++r) {
      const int q = (quad << 2) + r;
      Opart[obase + (size_t)q * 64 + d] = acc[dj][r];
    }
  }

  // ---- epilogue: l/l2 reduce (buffers alias Plds), write partials ----
  float* lbuf = Sbuf;          // [8w][8g][16q]  4 KB
  float* l2buf = Sbuf + 1024;  // [8w][8g][16q]  4 KB
#pragma unroll
  for (int gg = 0; gg < 8; ++gg) {
    float l = lacc[gg];
    l += __shfl_xor(l, 16, 64);
    l += __shfl_xor(l, 32, 64);
    float l2 = l2acc[gg];
    l2 += __shfl_xor(l2, 16, 64);
    l2 += __shfl_xor(l2, 32, 64);
    if (quad == 0) {
      lbuf[(w << 7) + (gg << 4) + lr] = l;
      l2buf[(w << 7) + (gg << 4) + lr] = l2;
    }
  }
  __syncthreads();
  if (lane < 16) {  // wave w reduces its own g
    float l = 0.f, l2 = 0.f;
#pragma unroll
    for (int w2 = 0; w2 < 8; ++w2) {
      l += lbuf[(w2 << 7) + (g << 4) + lr];
      l2 += l2buf[(w2 << 7) + (g << 4) + lr];
    }
    const size_t li = (((size_t)(tq << 5) + bg) << 10) + q0 + lr;
    lpart[li] = l;
    l2part[li] = l2;
  }
}

// ------- y = al*(Onorm @ Wp^T) + bias2, 64x64 tiles, 512 blocks.
// combine_o folded in; InstanceNorm stats from lpart/l2part in prologue;
// depth-1 register prefetch (prologue stats give extra cover). ----
__global__ __launch_bounds__(256) void gemm_proj(
    const float* __restrict__ Opart, const u16* __restrict__ wpb,
    const float* __restrict__ lpart, const float* __restrict__ l2part,
    const float* __restrict__ gamma, const float* __restrict__ beta,
    const float* __restrict__ ws, const float* __restrict__ bp,
    const float* __restrict__ vsum, float* __restrict__ y) {
  const int b = blockIdx.z;
  const int m0 = blockIdx.y << 6;  // o: 8 tiles
  const int n0 = blockIdx.x << 6;  // t: 16 tiles
  const int gidx = blockIdx.x >> 1;
  const int bg = (b << 3) + gidx;
  __shared__ __align__(16) u16 As[64][72];
  __shared__ __align__(16) u16 Bs[64][72];
  __shared__ float red[4];
  __shared__ float albc[2];
  __shared__ float b2s[64];
  __shared__ float linvS[512];
  const int tid = threadIdx.x;
  const int w = tid >> 6, lane = tid & 63, lr = lane & 15, lq = lane >> 4;
  const int mw = (w >> 1) << 5, nw = (w & 1) << 5;
  u16x8 rA[2];
  f32x4 rB[2][2][2];  // [it][tq][lo/hi f32x4]
#define LOADP(K)                                                            \
  {                                                                         \
    _Pragma("unroll") for (int it = 0; it < 2; ++it) {                      \
      const int e = tid + (it << 8);                                        \
      const int r = e >> 3, c8 = (e & 7) << 3;                              \
      rA[it] = *(const u16x8*)(wpb + (size_t)(m0 + r) * C_ + (K) + c8);     \
      const int q = (((n0 + r) & 127) << 3) + ((K) >> 6);                   \
      _Pragma("unroll") for (int tq = 0; tq < 2; ++tq) {                    \
        const float* src =                                                  \
            Opart + ((((size_t)((tq << 5) + bg)) << 10) + q) * 64 + c8;     \
        rB[it][tq][0] = *(const f32x4*)(src);                               \
        rB[it][tq][1] = *(const f32x4*)(src + 4);                           \
      }                                                                     \
    }                                                                       \
  }
  LOADP(0);  // in flight under the prologue stats
  // ---- prologue: ssq reduce over full 1024 q (from partials) ----
  {
    const size_t p0 = ((size_t)bg) << 10, p1 = ((size_t)(32 + bg)) << 10;
    const f32x4 la = *(const f32x4*)(lpart + p0 + (tid << 2));
    const f32x4 lb = *(const f32x4*)(lpart + p1 + (tid << 2));
    const f32x4 l2a = *(const f32x4*)(l2part + p0 + (tid << 2));
    const f32x4 l2b = *(const f32x4*)(l2part + p1 + (tid << 2));
    float ssq = 0.f;
#pragma unroll
    for (int k = 0; k < 4; ++k) {
      const float l = la[k] + lb[k];
      ssq += (l2a[k] + l2b[k]) / (l * l);
    }
#pragma unroll
    for (int off = 32; off; off >>= 1) ssq += __shfl_xor(ssq, off, 64);
    if (lane == 0) red[w] = ssq;
    // linv for this block's 512-q window (qb0 = (n0&127)*8 = 0 or 512)
    const int qb0 = (n0 & 127) << 3;
#pragma unroll
    for (int j = 0; j < 2; ++j) {
      const int qq = (tid << 1) + j;
      const float l = lpart[p0 + qb0 + qq] + lpart[p1 + qb0 + qq];
      linvS[qq] = 1.f / l;
    }
  }
  __syncthreads();
  if (tid == 0) {
    const float s = red[0] + red[1] + red[2] + red[3];
    const float mean = 0.0009765625f;
    const float var = s * (1.f / 1048576.f) - mean * mean;
    const float al = gamma[gidx] * rsqrtf(var + EPS_);
    albc[0] = al;
    albc[1] = beta[gidx] - al * mean;
  }
  __syncthreads();
  if (tid < 64) {
    const int o = m0 + tid;
    const float* wr = ws + (o << 6);
    const float* vsr = vsum + (bg << 6);
    float acc = 0.f;
#pragma unroll
    for (int d = 0; d < 64; d += 4) {
      const float4 vv4 = *(const float4*)(vsr + d);
      const float4 ws4 = *(const float4*)(wr + d);
      acc += ws4.x * vv4.x + ws4.y * vv4.y + ws4.z * vv4.z + ws4.w * vv4.w;
    }
    b2s[tid] = bp[o] + albc[1] * acc;
  }
  f32x4 acc[2][2] = {};
  for (int k0 = 0; k0 < C_; k0 += 64) {
    if (k0) BARSYNC();
    __syncthreads();  // k0==0: b2s/linvS visible; k0>0: harmless extra sync
#pragma unroll
    for (int it = 0; it < 2; ++it) {
      const int e = tid + (it << 8);
      const int r = e >> 3, c8 = (e & 7) << 3;
      *(u16x8*)&As[r][c8] = rA[it];
      const float li = linvS[(r << 3) + (k0 >> 6)];
      u16x8 o;
#pragma unroll
      for (int k = 0; k < 4; ++k) {
        o[k] = f2bf((rB[it][0][0][k] + rB[it][1][0][k]) * li);
        o[k + 4] = f2bf((rB[it][0][1][k] + rB[it][1][1][k]) * li);
      }
      *(u16x8*)&Bs[r][c8] = o;
    }
    if (k0 < C_ - 64) LOADP(k0 + 64);  // in flight across MFMA phase
    BARSYNC();
#pragma unroll
    for (int kf = 0; kf < 2; ++kf) {
      const int ko = (kf << 5) + (lq << 3);
      s16x8 a[2], bb[2];
#pragma unroll
      for (int i = 0; i < 2; ++i) a[i] = *(const s16x8*)&As[mw + (i << 4) + lr][ko];
#pragma unroll
      for (int j = 0; j < 2; ++j) bb[j] = *(const s16x8*)&Bs[nw + (j << 4) + lr][ko];
#pragma unroll
      for (int i = 0; i < 2; ++i)
#pragma unroll
        for (int j = 0; j < 2; ++j) acc[i][j] = mfma16(a[i], bb[j], acc[i][j]);
    }
  }
#undef LOADP
  const float al = albc[0];
#pragma unroll
  for (int i = 0; i < 2; ++i) {
    const int row = mw + (i << 4) + (lq << 2);
#pragma unroll
    for (int j = 0; j < 2; ++j) {
      const int col = nw + (j << 4) + lr;
#pragma unroll
      for (int r = 0; r < 4; ++r)
        y[(size_t)b * (C_ * (size_t)T_) + (size_t)(m0 + row + r) * T_ + n0 + col] =
            acc[i][j][r] * al + b2s[row + r];
    }
  }
}

extern "C" void kernel_launch(void* const* d_in, const int* in_sizes, int n_in,
                              void* d_out, int out_size, void* d_ws,
                              size_t ws_size, hipStream_t stream) {
  const float* x = (const float*)d_in[0];
  const float* wq = (const float*)d_in[1];
  const float* wk = (const float*)d_in[2];
  const float* wv = (const float*)d_in[3];
  const float* wh = (const float*)d_in[4];
  const float* gm = (const float*)d_in[5];
  const float* bt = (const float*)d_in[6];
  const float* wp = (const float*)d_in[7];
  const float* bp = (const float*)d_in[8];
  float* y = (float*)d_out;
  char* wsb = (char*)d_ws;

  u16* Qt = (u16*)(wsb + QT_OFF);
  u16* KS = (u16*)(wsb + KS_OFF);
  u16* VS = (u16*)(wsb + VS_OFF);
  u16* Xt = (u16*)(wsb + XT_OFF);
  float* vsum = (float*)(wsb + VSUM_OFF);
  u16* Wb = (u16*)(wsb + WB_OFF);
  u16* WQb = Wb;
  u16* WKb = Wb + 262144;
  u16* WVb = Wb + 524288;
  u16* WPb = Wb + 786432;
  float* lpart = (float*)(wsb + LP_OFF);
  float* l2part = (float*)(wsb + L2P_OFF);
  float* ws = (float*)(wsb + WS_OFF);
  float* Opart = (float*)(wsb + OP_OFF);

  prep_k<<<dim3(1152), 256, 0, stream>>>(x, wq, wk, wv, wp, Wb, ws, vsum, Xt);
  gemm_qkv<<<dim3(8, 8, 12), 256, 0, stream>>>(Xt, WQb, WKb, WVb, Qt, KS, VS,
                                               vsum);
  attn_fused<<<dim3(512), 512, 0, stream>>>(Qt, KS, VS, wh, Opart, lpart,
                                            l2part);
  gemm_proj<<<dim3(16, 8, 4), 256, 0, stream>>>(Opart, WPb, lpart, l2part, gm,
                                                bt, ws, bp, vsum, y);
}

// Round 16
// 148.565 us; speedup vs baseline: 1.0505x; 1.0505x over previous
//
#include <hip/hip_runtime.h>
#include <hip/hip_bf16.h>

#define B_ 4
#define C_ 512
#define T_ 1024
#define SCALE_ 0.125f
#define EPS_ 1e-5f

typedef unsigned short u16;
typedef __attribute__((ext_vector_type(8))) unsigned short u16x8;
typedef __attribute__((ext_vector_type(4))) unsigned short u16x4;
typedef __attribute__((ext_vector_type(8))) short s16x8;
typedef __attribute__((ext_vector_type(4))) float f32x4;

// ws byte offsets (ws is 256 MiB)
#define QT_OFF    (0x0ull)         // bf16 Qt[B][T][C]   4 MB (Q pre-scaled by 1/8)
#define KS_OFF    (0x400000ull)    // bf16 KS swizzled [B][t32][half][f][lane][8] 4 MB
#define VS_OFF    (0x800000ull)    // bf16 VS swizzled [B][g][t32][dj][lane][8]   4 MB
#define XT_OFF    (0xC00000ull)    // bf16 Xt[B][T][C]   4 MB
#define WB_OFF    (0x1480000ull)   // bf16 W[4][512][512]: wq,wk,wv,wp  2 MB
#define LP_OFF    (0x1680000ull)   // fp32 lpart [2][32][1024] 256 KB
#define L2P_OFF   (0x1700000ull)   // fp32 l2part[2][32][1024] 256 KB
#define WS_OFF    (0x1780000ull)   // fp32 ws[512][64] 128 KB
#define VSUM_OFF  (0x17A0000ull)   // fp32 vsum[B][8][64] 8 KB
#define OP_OFF    (0x2000000ull)   // fp32 Opart[2][32][1024][64] 16 MB

static __device__ __forceinline__ u16 f2bf(float f) {
  unsigned u = __float_as_uint(f);
  unsigned r = (u + 0x7fff + ((u >> 16) & 1)) >> 16;  // RNE
  return (u16)r;
}
static __device__ __forceinline__ float b2f(u16 x) {
  return __uint_as_float(((unsigned)x) << 16);
}
static __device__ __forceinline__ f32x4 mfma16(s16x8 a, s16x8 b, f32x4 c) {
  return __builtin_amdgcn_mfma_f32_16x16x32_bf16(a, b, c, 0, 0, 0);
}
// lgkmcnt(0) + raw barrier: LDS ops ordered, but in-flight GLOBAL loads (to
// regs) legitimately cross the barrier -- the T3 pipeline primitive.
#define BARSYNC()                                       \
  {                                                     \
    asm volatile("s_waitcnt lgkmcnt(0)" ::: "memory");  \
    __builtin_amdgcn_s_barrier();                       \
  }

// ---- prep: blocks [0,512) wcvt; [512,640) wsum+vsum-zero; [640,1152)
// transpose x -> Xt[b][t][c] bf16. Branch is block-uniform. ----
__global__ __launch_bounds__(256) void prep_k(
    const float* __restrict__ x, const float* __restrict__ wq,
    const float* __restrict__ wk, const float* __restrict__ wv,
    const float* __restrict__ wp, u16* __restrict__ wb,
    float* __restrict__ ws, float* __restrict__ vsum, u16* __restrict__ xt) {
  const int id = blockIdx.x;
  const int tid = threadIdx.x;
  __shared__ float Ts[64][65];
  if (id < 512) {  // ---- wcvt: fp32 -> bf16, 4 weight matrices ----
    const int i = (id << 8) + tid;
    const int idx = i << 3;
    const int which = idx >> 18;  // uniform per block
    const int off = idx & 262143;
    const float* s = which == 0 ? wq : which == 1 ? wk : which == 2 ? wv : wp;
    const float4 f0 = *(const float4*)(s + off);
    const float4 f1 = *(const float4*)(s + off + 4);
    u16x8 o;
    o[0] = f2bf(f0.x); o[1] = f2bf(f0.y); o[2] = f2bf(f0.z); o[3] = f2bf(f0.w);
    o[4] = f2bf(f1.x); o[5] = f2bf(f1.y); o[6] = f2bf(f1.z); o[7] = f2bf(f1.w);
    *(u16x8*)(wb + idx) = o;
  } else if (id < 640) {  // ---- ws[o][d] = sum_j wp[o][j*64+d]; zero vsum ----
    const int idx = ((id - 512) << 8) + tid;
    if (id - 512 < 8) vsum[idx] = 0.f;
    const int o = idx >> 6, d = idx & 63;
    float s = 0.f;
#pragma unroll
    for (int j = 0; j < 8; ++j) s += wp[(o << 9) + (j << 6) + d];
    ws[idx] = s;
  } else {  // ---- transpose x[b][c][t] -> Xt[b][t][c] bf16 ----
    const int id3 = id - 640;
    const int b = id3 >> 7, rem = id3 & 127;
    const int t0 = (rem & 15) << 6;
    const int c0 = (rem >> 4) << 6;
    const float* __restrict__ X = x + (size_t)b * (C_ * (size_t)T_);
    u16* __restrict__ Xt = xt + (size_t)b * (T_ * (size_t)C_);
#pragma unroll
    for (int i = 0; i < 4; ++i) {
      const int e = tid + (i << 8);
      const int r = e >> 4, c4 = e & 15;
      const float4 v =
          *(const float4*)(X + (size_t)(c0 + r) * T_ + t0 + (c4 << 2));
      Ts[r][(c4 << 2) + 0] = v.x; Ts[r][(c4 << 2) + 1] = v.y;
      Ts[r][(c4 << 2) + 2] = v.z; Ts[r][(c4 << 2) + 3] = v.w;
    }
    __syncthreads();
#pragma unroll
    for (int i = 0; i < 2; ++i) {
      const int e = tid + (i << 8);
      const int tt = e >> 3, c8 = e & 7;
      u16x8 o;
#pragma unroll
      for (int j = 0; j < 8; ++j) o[j] = f2bf(Ts[(c8 << 3) + j][tt]);
      *(u16x8*)(Xt + (size_t)(t0 + tt) * C_ + c0 + (c8 << 3)) = o;
    }
  }
}

// ---- unified QKV GEMM, 128x64 tiles, 768 blocks (3/CU), DEPTH-2 REGISTER
// PREFETCH (ping-pong reg sets, loop body doubled for static indexing).
// Q epilogue through LDS -> coalesced u16x8 stores. ----
__global__ __launch_bounds__(256) void gemm_qkv(
    const u16* __restrict__ xt, const u16* __restrict__ wqb,
    const u16* __restrict__ wkb, const u16* __restrict__ wvb,
    u16* __restrict__ qto, u16* __restrict__ ks, u16* __restrict__ vs,
    float* __restrict__ vsum) {
  const int z = blockIdx.z;
  const int tid = threadIdx.x;
  const int w = tid >> 6, lane = tid & 63, lr = lane & 15, lq = lane >> 4;
  const int wm = (w >> 1) << 6, wn = (w & 1) << 5;  // 2x2 waves: 64m x 32n
  __shared__ __align__(16) u16 As[128][72];
  __shared__ __align__(16) u16 Bs[64][72];
  u16* Ts = &As[0][0];  // epilogue staging tile [128][72] (aliases As)
  const u16 *Ag, *Bg;
  int m0, n0, mode, b;
  if (z < 8) {
    const int which = z >> 2;
    b = z & 3;
    Ag = xt + (size_t)b * (T_ * (size_t)C_);
    m0 = blockIdx.x << 7;  // t: 8 tiles
    Bg = which ? wkb : wqb;
    n0 = blockIdx.y << 6;  // o: 8 tiles
    mode = which;          // 0 = Q, 1 = K
  } else {
    b = z - 8;
    const int ti = (blockIdx.y << 3) | blockIdx.x;  // [0,64)
    Ag = wvb;
    m0 = (ti >> 4) << 7;  // o: 4 tiles
    Bg = xt + (size_t)b * (T_ * (size_t)C_);
    n0 = (ti & 15) << 6;  // t: 16 tiles
    mode = 2;
  }
  u16x8 rA0[4], rB0[2], rA1[4], rB1[2];
#define LOADQ(RA, RB, K)                                                  \
  {                                                                       \
    _Pragma("unroll") for (int it = 0; it < 4; ++it) {                    \
      const int e = tid + (it << 8);                                      \
      const int r = e >> 3, c8 = (e & 7) << 3;                            \
      RA[it] = *(const u16x8*)(Ag + (size_t)(m0 + r) * C_ + (K) + c8);    \
    }                                                                     \
    _Pragma("unroll") for (int it = 0; it < 2; ++it) {                    \
      const int e = tid + (it << 8);                                      \
      const int r = e >> 3, c8 = (e & 7) << 3;                            \
      RB[it] = *(const u16x8*)(Bg + (size_t)(n0 + r) * C_ + (K) + c8);    \
    }                                                                     \
  }
#define WRITEQ(RA, RB)                                       \
  {                                                          \
    _Pragma("unroll") for (int it = 0; it < 4; ++it) {       \
      const int e = tid + (it << 8);                         \
      *(u16x8*)&As[e >> 3][(e & 7) << 3] = RA[it];           \
    }                                                        \
    _Pragma("unroll") for (int it = 0; it < 2; ++it) {       \
      const int e = tid + (it << 8);                         \
      *(u16x8*)&Bs[e >> 3][(e & 7) << 3] = RB[it];           \
    }                                                        \
  }
#define MFMAQ()                                                                \
  {                                                                            \
    _Pragma("unroll") for (int kf = 0; kf < 2; ++kf) {                         \
      const int ko = (kf << 5) + (lq << 3);                                    \
      s16x8 a[4], bb[2];                                                       \
      _Pragma("unroll") for (int i = 0; i < 4; ++i) a[i] =                     \
          *(const s16x8*)&As[wm + (i << 4) + lr][ko];                          \
      _Pragma("unroll") for (int j = 0; j < 2; ++j) bb[j] =                    \
          *(const s16x8*)&Bs[wn + (j << 4) + lr][ko];                          \
      _Pragma("unroll") for (int i = 0; i < 4; ++i)                            \
          _Pragma("unroll") for (int j = 0; j < 2; ++j) acc[i][j] =            \
              mfma16(a[i], bb[j], acc[i][j]);                                  \
    }                                                                          \
  }
  f32x4 acc[4][2] = {};
  LOADQ(rA0, rB0, 0);
  LOADQ(rA1, rB1, 64);
  for (int k0 = 0; k0 < C_; k0 += 128) {
    // even K-step (k0)
    if (k0) BARSYNC();  // prev reads consumed (all waves)
    WRITEQ(rA0, rB0);
    if (k0 + 128 < C_) LOADQ(rA0, rB0, k0 + 128);  // 2 phases of cover
    BARSYNC();  // writes committed
    MFMAQ();
    // odd K-step (k0+64)
    BARSYNC();
    WRITEQ(rA1, rB1);
    if (k0 + 192 < C_) LOADQ(rA1, rB1, k0 + 192);
    BARSYNC();
    MFMAQ();
  }
#undef LOADQ
#undef WRITEQ
#undef MFMAQ
  if (mode == 2) {
    // ---- vsum contribution: sum over this tile's 64 t-cols, atomic ----
#pragma unroll
    for (int i = 0; i < 4; ++i)
#pragma unroll
      for (int r = 0; r < 4; ++r) {
        float s = acc[i][0][r] + acc[i][1][r];
        s += __shfl_xor(s, 1, 64);
        s += __shfl_xor(s, 2, 64);
        s += __shfl_xor(s, 4, 64);
        s += __shfl_xor(s, 8, 64);
        if (lr == 0) {
          const int o = m0 + wm + (i << 4) + (lq << 2) + r;
          atomicAdd(&vsum[(((b << 3) | (o >> 6)) << 6) | (o & 63)], s);
        }
      }
  }
  BARSYNC();  // all waves done reading As before Ts overwrite
  // ---- stage output tile [m_local 128][n_local 64] (stride 72) in LDS ----
  const float osc = (mode == 0) ? SCALE_ : 1.0f;
#pragma unroll
  for (int i = 0; i < 4; ++i)
#pragma unroll
    for (int j = 0; j < 2; ++j)
#pragma unroll
      for (int r = 0; r < 4; ++r)
        Ts[(wm + (i << 4) + (lq << 2) + r) * 72 + wn + (j << 4) + lr] =
            f2bf(acc[i][j][r] * osc);
  __syncthreads();
  if (mode == 0) {
    // coalesced Qt store: row = tid>>1, col-half = (tid&1)*32; 4 u16x8 each
    u16* Y = qto + (size_t)b * (T_ * (size_t)C_);
    const int row = tid >> 1, ch32 = (tid & 1) << 5;
    u16* dst = Y + (size_t)(m0 + row) * C_ + n0 + ch32;
    const u16* src = &Ts[row * 72 + ch32];
#pragma unroll
    for (int u = 0; u < 4; ++u)
      *(u16x8*)(dst + (u << 3)) = *(const u16x8*)(src + (u << 3));
    return;
  }
  const int ch = tid >> 4, part = tid & 15;  // 16 chunks x 16 threads
  if (mode == 1) {
    // chunk = (t32l[4], half[2], fl[2]); lanek = u*16+part -> coalesced
    const int t32l = ch >> 2, half = (ch >> 1) & 1, fl = ch & 1;
    const int t32g = (m0 >> 5) + t32l, fg = (n0 >> 5) + fl;
    u16* dst =
        ks + (((((size_t)((b << 5) | t32g) << 1) | half) << 4 | fg) << 9);
#pragma unroll
    for (int u = 0; u < 4; ++u) {
      const int lanek = (u << 4) + part;
      const int quadk = lanek >> 4, lrk = lanek & 15;
      const int rr = ((lrk >> 2) << 3) | (half << 2) | (lrk & 3);
      const u16x8 v =
          *(const u16x8*)&Ts[((t32l << 5) + rr) * 72 + (fl << 5) + (quadk << 3)];
      *(u16x8*)(dst + (lanek << 3)) = v;
    }
  } else {
    // chunk = (gl[2], t32l[2], dj[4]); lanev = u*16+part -> coalesced
    const int gl = ch >> 3, t32l = (ch >> 2) & 1, dj = ch & 3;
    const int gg = (m0 >> 6) + gl, t32g = (n0 >> 5) + t32l;
    u16* dst =
        vs + (((((size_t)((b << 3) | gg) << 5) | t32g) << 2 | dj) << 9);
#pragma unroll
    for (int u = 0; u < 4; ++u) {
      const int lanev = (u << 4) + part;
      const int quadv = lanev >> 4, lrv = lanev & 15;
      const u16x8 v = *(const u16x8*)&Ts[((gl << 6) + (dj << 4) + lrv) * 72 +
                                         (t32l << 5) + (quadv << 3)];
      *(u16x8*)(dst + (lanev << 3)) = v;
    }
  }
}

// ---- FUSED attention: exact R14 structure (47.9us, 56 VGPR, no spill --
// R15's 16-frag V-prefetch demanded ~120 VGPR and the allocator clamped to
// 64 + spilled: FETCH 10->51MB, WRITE 17->99MB, 57us. Reg-prefetch beyond
// ~8 spare VGPRs is unavailable in this kernel). Added: T5 s_setprio(1)
// around the PV MFMA cluster -- zero-register; helps when co-resident
// blocks are phase-offset (2 independent blocks/CU here; m191 attn +4-7%).
__global__ __launch_bounds__(512, 4) void attn_fused(
    const u16* __restrict__ Qt, const u16* __restrict__ KS,
    const u16* __restrict__ VS, const float* __restrict__ wh,
    float* __restrict__ Opart, float* __restrict__ lpart,
    float* __restrict__ l2part) {
  const int id = blockIdx.x;
  const int xcd = id & 7;
  const int b = xcd >> 1;
  const int hi = id >> 3;                       // [0,64)
  const int qb = ((xcd & 1) << 5) | (hi & 31);  // [0,64)
  const int tq = hi >> 5;                       // [0,2) t-half
  const int q0 = qb << 4;
  const int tid = threadIdx.x;
  const int w = tid >> 6, lane = tid & 63;
  const int lr = lane & 15, quad = lane >> 4;

  __shared__ __align__(16) u16 Qs[16][522];       // 16704 B
  __shared__ __align__(16) u16 Plds[8][16][136];  // 34816 B
  float* Sbuf = (float*)&Plds[0][0][0];  // epilogue alias (Plds dead by then)

  {  // stage Q tile (16 x 512)
    const u16* Qb = Qt + ((size_t)b * T_ + q0) * C_;
    for (int i = tid; i < 1024; i += 512) {
      const int r = i >> 6, c8 = i & 63;
      *(u16x8*)&Qs[r][c8 << 3] = *(const u16x8*)(Qb + (size_t)r * C_ + (c8 << 3));
    }
  }

  const u16* __restrict__ Qrow = &Qs[lr][quad << 3];
  const int g = w;  // PV head owned by this wave
  const int win = w >> 1, half = w & 1;  // QK: window pair, K-half
  const u16* __restrict__ Vc =
      VS + (((size_t)((b << 3) | g)) << 16) + (lane << 3);

  float lacc[8] = {}, l2acc[8] = {};
  f32x4 acc[4] = {};

  __syncthreads();

  for (int c = 0; c < 4; ++c) {
    // ---- QK + mix + exp: K loads lane-contiguous from KS ----
    const int t32k = (tq << 4) + (c << 2) + win;
    const u16* __restrict__ Kc =
        KS + (((size_t)((((b << 5) | t32k) << 1) | half)) << 13) + (lane << 3);
    f32x4 m[8] = {};
#pragma unroll 4
    for (int h = 0; h < 8; ++h) {
      f32x4 a0 = {0.f, 0.f, 0.f, 0.f};
      const s16x8 qf0 = *(const s16x8*)(Qrow + (h << 6));
      const s16x8 k0 = *(const s16x8*)(Kc + (h << 10));
      a0 = mfma16(k0, qf0, a0);
      const s16x8 qf1 = *(const s16x8*)(Qrow + (h << 6) + 32);
      const s16x8 k1 = *(const s16x8*)(Kc + (h << 10) + 512);
      a0 = mfma16(k1, qf1, a0);
#pragma unroll
      for (int gg = 0; gg < 8; ++gg) {
        const float wgh = wh[(gg << 3) + h];  // uniform -> SGPR
        m[gg] += a0 * wgh;
      }
    }
    // lane's t slots: win*32 + quad*8 + half*4 + {0..3}; q = lr
#pragma unroll
    for (int gg = 0; gg < 8; ++gg) {
      f32x4 e0;
#pragma unroll
      for (int k = 0; k < 4; ++k) e0[k] = __expf(m[gg][k]);
      u16x4 o;
#pragma unroll
      for (int k = 0; k < 4; ++k) o[k] = f2bf(e0[k]);
      *(u16x4*)&Plds[gg][lr][(win << 5) + (quad << 3) + (half << 2)] = o;
      lacc[gg] += e0[0] + e0[1] + e0[2] + e0[3];
      l2acc[gg] += e0[0] * e0[0] + e0[1] * e0[1] + e0[2] * e0[2] + e0[3] * e0[3];
    }
    __syncthreads();  // P ready
    // ---- PV: V loads lane-contiguous from VS; prio-boosted MFMA ----
    __builtin_amdgcn_s_setprio(1);
#pragma unroll
    for (int tw = 0; tw < 4; ++tw) {
      const int t32v = (tq << 4) + (c << 2) + tw;
      const s16x8 pa = *(const s16x8*)&Plds[g][lr][(tw << 5) + (quad << 3)];
#pragma unroll
      for (int dj = 0; dj < 4; ++dj) {
        const s16x8 vb =
            *(const s16x8*)(Vc + ((size_t)t32v << 11) + (dj << 9));
        acc[dj] = mfma16(pa, vb, acc[dj]);
      }
    }
    __builtin_amdgcn_s_setprio(0);
    __syncthreads();  // P consumed, safe to overwrite next chunk
  }

  // ---- write raw f32 partial O (normalization happens in gemm_proj) ----
  const int bg = (b << 3) + g;
  const size_t obase = ((((size_t)(tq << 5) + bg) << 10) + q0) * 64;
#pragma unroll
  for (int dj = 0; dj < 4; ++dj) {
    const int d = (dj << 4) + lr;
#pragma unroll
    for (int r = 0; r < 4; ++r) {
      const int q = (quad << 2) + r;
      Opart[obase + (size_t)q * 64 + d] = acc[dj][r];
    }
  }

  // ---- epilogue: l/l2 reduce (buffers alias Plds), write partials ----
  float* lbuf = Sbuf;          // [8w][8g][16q]  4 KB
  float* l2buf = Sbuf + 1024;  // [8w][8g][16q]  4 KB
#pragma unroll
  for (int gg = 0; gg < 8; ++gg) {
    float l = lacc[gg];
    l += __shfl_xor(l, 16, 64);
    l += __shfl_xor(l, 32, 64);
    float l2 = l2acc[gg];
    l2 += __shfl_xor(l2, 16, 64);
    l2 += __shfl_xor(l2, 32, 64);
    if (quad == 0) {
      lbuf[(w << 7) + (gg << 4) + lr] = l;
      l2buf[(w << 7) + (gg << 4) + lr] = l2;
    }
  }
  __syncthreads();
  if (lane < 16) {  // wave w reduces its own g
    float l = 0.f, l2 = 0.f;
#pragma unroll
    for (int w2 = 0; w2 < 8; ++w2) {
      l += lbuf[(w2 << 7) + (g << 4) + lr];
      l2 += l2buf[(w2 << 7) + (g << 4) + lr];
    }
    const size_t li = (((size_t)(tq << 5) + bg) << 10) + q0 + lr;
    lpart[li] = l;
    l2part[li] = l2;
  }
}

// ------- y = al*(Onorm @ Wp^T) + bias2, 64x64 tiles, 512 blocks.
// combine_o folded in; InstanceNorm stats from lpart/l2part in prologue;
// depth-1 register prefetch (prologue stats give extra cover). ----
__global__ __launch_bounds__(256) void gemm_proj(
    const float* __restrict__ Opart, const u16* __restrict__ wpb,
    const float* __restrict__ lpart, const float* __restrict__ l2part,
    const float* __restrict__ gamma, const float* __restrict__ beta,
    const float* __restrict__ ws, const float* __restrict__ bp,
    const float* __restrict__ vsum, float* __restrict__ y) {
  const int b = blockIdx.z;
  const int m0 = blockIdx.y << 6;  // o: 8 tiles
  const int n0 = blockIdx.x << 6;  // t: 16 tiles
  const int gidx = blockIdx.x >> 1;
  const int bg = (b << 3) + gidx;
  __shared__ __align__(16) u16 As[64][72];
  __shared__ __align__(16) u16 Bs[64][72];
  __shared__ float red[4];
  __shared__ float albc[2];
  __shared__ float b2s[64];
  __shared__ float linvS[512];
  const int tid = threadIdx.x;
  const int w = tid >> 6, lane = tid & 63, lr = lane & 15, lq = lane >> 4;
  const int mw = (w >> 1) << 5, nw = (w & 1) << 5;
  u16x8 rA[2];
  f32x4 rB[2][2][2];  // [it][tq][lo/hi f32x4]
#define LOADP(K)                                                            \
  {                                                                         \
    _Pragma("unroll") for (int it = 0; it < 2; ++it) {                      \
      const int e = tid + (it << 8);                                        \
      const int r = e >> 3, c8 = (e & 7) << 3;                              \
      rA[it] = *(const u16x8*)(wpb + (size_t)(m0 + r) * C_ + (K) + c8);     \
      const int q = (((n0 + r) & 127) << 3) + ((K) >> 6);                   \
      _Pragma("unroll") for (int tq = 0; tq < 2; ++tq) {                    \
        const float* src =                                                  \
            Opart + ((((size_t)((tq << 5) + bg)) << 10) + q) * 64 + c8;     \
        rB[it][tq][0] = *(const f32x4*)(src);                               \
        rB[it][tq][1] = *(const f32x4*)(src + 4);                           \
      }                                                                     \
    }                                                                       \
  }
  LOADP(0);  // in flight under the prologue stats
  // ---- prologue: ssq reduce over full 1024 q (from partials) ----
  {
    const size_t p0 = ((size_t)bg) << 10, p1 = ((size_t)(32 + bg)) << 10;
    const f32x4 la = *(const f32x4*)(lpart + p0 + (tid << 2));
    const f32x4 lb = *(const f32x4*)(lpart + p1 + (tid << 2));
    const f32x4 l2a = *(const f32x4*)(l2part + p0 + (tid << 2));
    const f32x4 l2b = *(const f32x4*)(l2part + p1 + (tid << 2));
    float ssq = 0.f;
#pragma unroll
    for (int k = 0; k < 4; ++k) {
      const float l = la[k] + lb[k];
      ssq += (l2a[k] + l2b[k]) / (l * l);
    }
#pragma unroll
    for (int off = 32; off; off >>= 1) ssq += __shfl_xor(ssq, off, 64);
    if (lane == 0) red[w] = ssq;
    // linv for this block's 512-q window (qb0 = (n0&127)*8 = 0 or 512)
    const int qb0 = (n0 & 127) << 3;
#pragma unroll
    for (int j = 0; j < 2; ++j) {
      const int qq = (tid << 1) + j;
      const float l = lpart[p0 + qb0 + qq] + lpart[p1 + qb0 + qq];
      linvS[qq] = 1.f / l;
    }
  }
  __syncthreads();
  if (tid == 0) {
    const float s = red[0] + red[1] + red[2] + red[3];
    const float mean = 0.0009765625f;
    const float var = s * (1.f / 1048576.f) - mean * mean;
    const float al = gamma[gidx] * rsqrtf(var + EPS_);
    albc[0] = al;
    albc[1] = beta[gidx] - al * mean;
  }
  __syncthreads();
  if (tid < 64) {
    const int o = m0 + tid;
    const float* wr = ws + (o << 6);
    const float* vsr = vsum + (bg << 6);
    float acc = 0.f;
#pragma unroll
    for (int d = 0; d < 64; d += 4) {
      const float4 vv4 = *(const float4*)(vsr + d);
      const float4 ws4 = *(const float4*)(wr + d);
      acc += ws4.x * vv4.x + ws4.y * vv4.y + ws4.z * vv4.z + ws4.w * vv4.w;
    }
    b2s[tid] = bp[o] + albc[1] * acc;
  }
  f32x4 acc[2][2] = {};
  for (int k0 = 0; k0 < C_; k0 += 64) {
    if (k0) BARSYNC();
    __syncthreads();  // k0==0: b2s/linvS visible; k0>0: harmless extra sync
#pragma unroll
    for (int it = 0; it < 2; ++it) {
      const int e = tid + (it << 8);
      const int r = e >> 3, c8 = (e & 7) << 3;
      *(u16x8*)&As[r][c8] = rA[it];
      const float li = linvS[(r << 3) + (k0 >> 6)];
      u16x8 o;
#pragma unroll
      for (int k = 0; k < 4; ++k) {
        o[k] = f2bf((rB[it][0][0][k] + rB[it][1][0][k]) * li);
        o[k + 4] = f2bf((rB[it][0][1][k] + rB[it][1][1][k]) * li);
      }
      *(u16x8*)&Bs[r][c8] = o;
    }
    if (k0 < C_ - 64) LOADP(k0 + 64);  // in flight across MFMA phase
    BARSYNC();
#pragma unroll
    for (int kf = 0; kf < 2; ++kf) {
      const int ko = (kf << 5) + (lq << 3);
      s16x8 a[2], bb[2];
#pragma unroll
      for (int i = 0; i < 2; ++i) a[i] = *(const s16x8*)&As[mw + (i << 4) + lr][ko];
#pragma unroll
      for (int j = 0; j < 2; ++j) bb[j] = *(const s16x8*)&Bs[nw + (j << 4) + lr][ko];
#pragma unroll
      for (int i = 0; i < 2; ++i)
#pragma unroll
        for (int j = 0; j < 2; ++j) acc[i][j] = mfma16(a[i], bb[j], acc[i][j]);
    }
  }
#undef LOADP
  const float al = albc[0];
#pragma unroll
  for (int i = 0; i < 2; ++i) {
    const int row = mw + (i << 4) + (lq << 2);
#pragma unroll
    for (int j = 0; j < 2; ++j) {
      const int col = nw + (j << 4) + lr;
#pragma unroll
      for (int r = 0; r < 4; ++r)
        y[(size_t)b * (C_ * (size_t)T_) + (size_t)(m0 + row + r) * T_ + n0 + col] =
            acc[i][j][r] * al + b2s[row + r];
    }
  }
}

extern "C" void kernel_launch(void* const* d_in, const int* in_sizes, int n_in,
                              void* d_out, int out_size, void* d_ws,
                              size_t ws_size, hipStream_t stream) {
  const float* x = (const float*)d_in[0];
  const float* wq = (const float*)d_in[1];
  const float* wk = (const float*)d_in[2];
  const float* wv = (const float*)d_in[3];
  const float* wh = (const float*)d_in[4];
  const float* gm = (const float*)d_in[5];
  const float* bt = (const float*)d_in[6];
  const float* wp = (const float*)d_in[7];
  const float* bp = (const float*)d_in[8];
  float* y = (float*)d_out;
  char* wsb = (char*)d_ws;

  u16* Qt = (u16*)(wsb + QT_OFF);
  u16* KS = (u16*)(wsb + KS_OFF);
  u16* VS = (u16*)(wsb + VS_OFF);
  u16* Xt = (u16*)(wsb + XT_OFF);
  float* vsum = (float*)(wsb + VSUM_OFF);
  u16* Wb = (u16*)(wsb + WB_OFF);
  u16* WQb = Wb;
  u16* WKb = Wb + 262144;
  u16* WVb = Wb + 524288;
  u16* WPb = Wb + 786432;
  float* lpart = (float*)(wsb + LP_OFF);
  float* l2part = (float*)(wsb + L2P_OFF);
  float* ws = (float*)(wsb + WS_OFF);
  float* Opart = (float*)(wsb + OP_OFF);

  prep_k<<<dim3(1152), 256, 0, stream>>>(x, wq, wk, wv, wp, Wb, ws, vsum, Xt);
  gemm_qkv<<<dim3(8, 8, 12), 256, 0, stream>>>(Xt, WQb, WKb, WVb, Qt, KS, VS,
                                               vsum);
  attn_fused<<<dim3(512), 512, 0, stream>>>(Qt, KS, VS, wh, Opart, lpart,
                                            l2part);
  gemm_proj<<<dim3(16, 8, 4), 256, 0, stream>>>(Opart, WPb, lpart, l2part, gm,
                                                bt, ws, bp, vsum, y);
}

// Round 17
// 146.336 us; speedup vs baseline: 1.0665x; 1.0152x over previous
//
#include <hip/hip_runtime.h>
#include <hip/hip_bf16.h>

#define B_ 4
#define C_ 512
#define T_ 1024
#define SCALE_ 0.125f
#define EPS_ 1e-5f

typedef unsigned short u16;
typedef __attribute__((ext_vector_type(8))) unsigned short u16x8;
typedef __attribute__((ext_vector_type(4))) unsigned short u16x4;
typedef __attribute__((ext_vector_type(8))) short s16x8;
typedef __attribute__((ext_vector_type(4))) float f32x4;

// ws byte offsets (ws is 256 MiB)
#define QT_OFF    (0x0ull)         // bf16 Qt[B][T][C]   4 MB (Q pre-scaled by 1/8)
#define KS_OFF    (0x400000ull)    // bf16 KS swizzled [B][t32][half][f][lane][8] 4 MB
#define VS_OFF    (0x800000ull)    // bf16 VS swizzled [B][g][t32][dj][lane][8]   4 MB
#define XT_OFF    (0xC00000ull)    // bf16 Xt[B][T][C]   4 MB
#define WB_OFF    (0x1480000ull)   // bf16 W[4][512][512]: wq,wk,wv,wp  2 MB
#define LP_OFF    (0x1680000ull)   // fp32 lpart [2][32][1024] 256 KB
#define L2P_OFF   (0x1700000ull)   // fp32 l2part[2][32][1024] 256 KB
#define WS_OFF    (0x1780000ull)   // fp32 ws[512][64] 128 KB
#define VSUM_OFF  (0x17A0000ull)   // fp32 vsum[B][8][64] 8 KB
#define OP_OFF    (0x2000000ull)   // bf16 Opart[2][32][1024][64] 8 MB

static __device__ __forceinline__ u16 f2bf(float f) {
  unsigned u = __float_as_uint(f);
  unsigned r = (u + 0x7fff + ((u >> 16) & 1)) >> 16;  // RNE
  return (u16)r;
}
static __device__ __forceinline__ float b2f(u16 x) {
  return __uint_as_float(((unsigned)x) << 16);
}
static __device__ __forceinline__ f32x4 mfma16(s16x8 a, s16x8 b, f32x4 c) {
  return __builtin_amdgcn_mfma_f32_16x16x32_bf16(a, b, c, 0, 0, 0);
}
// lgkmcnt(0) + raw barrier: LDS ops ordered, but in-flight GLOBAL loads (to
// regs) legitimately cross the barrier -- the T3 pipeline primitive.
#define BARSYNC()                                       \
  {                                                     \
    asm volatile("s_waitcnt lgkmcnt(0)" ::: "memory");  \
    __builtin_amdgcn_s_barrier();                       \
  }

// ---- prep: blocks [0,512) wcvt; [512,640) wsum+vsum-zero; [640,1152)
// transpose x -> Xt[b][t][c] bf16. Branch is block-uniform. ----
__global__ __launch_bounds__(256) void prep_k(
    const float* __restrict__ x, const float* __restrict__ wq,
    const float* __restrict__ wk, const float* __restrict__ wv,
    const float* __restrict__ wp, u16* __restrict__ wb,
    float* __restrict__ ws, float* __restrict__ vsum, u16* __restrict__ xt) {
  const int id = blockIdx.x;
  const int tid = threadIdx.x;
  __shared__ float Ts[64][65];
  if (id < 512) {  // ---- wcvt: fp32 -> bf16, 4 weight matrices ----
    const int i = (id << 8) + tid;
    const int idx = i << 3;
    const int which = idx >> 18;  // uniform per block
    const int off = idx & 262143;
    const float* s = which == 0 ? wq : which == 1 ? wk : which == 2 ? wv : wp;
    const float4 f0 = *(const float4*)(s + off);
    const float4 f1 = *(const float4*)(s + off + 4);
    u16x8 o;
    o[0] = f2bf(f0.x); o[1] = f2bf(f0.y); o[2] = f2bf(f0.z); o[3] = f2bf(f0.w);
    o[4] = f2bf(f1.x); o[5] = f2bf(f1.y); o[6] = f2bf(f1.z); o[7] = f2bf(f1.w);
    *(u16x8*)(wb + idx) = o;
  } else if (id < 640) {  // ---- ws[o][d] = sum_j wp[o][j*64+d]; zero vsum ----
    const int idx = ((id - 512) << 8) + tid;
    if (id - 512 < 8) vsum[idx] = 0.f;
    const int o = idx >> 6, d = idx & 63;
    float s = 0.f;
#pragma unroll
    for (int j = 0; j < 8; ++j) s += wp[(o << 9) + (j << 6) + d];
    ws[idx] = s;
  } else {  // ---- transpose x[b][c][t] -> Xt[b][t][c] bf16 ----
    const int id3 = id - 640;
    const int b = id3 >> 7, rem = id3 & 127;
    const int t0 = (rem & 15) << 6;
    const int c0 = (rem >> 4) << 6;
    const float* __restrict__ X = x + (size_t)b * (C_ * (size_t)T_);
    u16* __restrict__ Xt = xt + (size_t)b * (T_ * (size_t)C_);
#pragma unroll
    for (int i = 0; i < 4; ++i) {
      const int e = tid + (i << 8);
      const int r = e >> 4, c4 = e & 15;
      const float4 v =
          *(const float4*)(X + (size_t)(c0 + r) * T_ + t0 + (c4 << 2));
      Ts[r][(c4 << 2) + 0] = v.x; Ts[r][(c4 << 2) + 1] = v.y;
      Ts[r][(c4 << 2) + 2] = v.z; Ts[r][(c4 << 2) + 3] = v.w;
    }
    __syncthreads();
#pragma unroll
    for (int i = 0; i < 2; ++i) {
      const int e = tid + (i << 8);
      const int tt = e >> 3, c8 = e & 7;
      u16x8 o;
#pragma unroll
      for (int j = 0; j < 8; ++j) o[j] = f2bf(Ts[(c8 << 3) + j][tt]);
      *(u16x8*)(Xt + (size_t)(t0 + tt) * C_ + c0 + (c8 << 3)) = o;
    }
  }
}

// ---- unified QKV GEMM, 128x64 tiles, 768 blocks (3/CU), DEPTH-2 REGISTER
// PREFETCH (ping-pong reg sets, loop body doubled for static indexing).
// Q epilogue through LDS -> coalesced u16x8 stores. ----
__global__ __launch_bounds__(256) void gemm_qkv(
    const u16* __restrict__ xt, const u16* __restrict__ wqb,
    const u16* __restrict__ wkb, const u16* __restrict__ wvb,
    u16* __restrict__ qto, u16* __restrict__ ks, u16* __restrict__ vs,
    float* __restrict__ vsum) {
  const int z = blockIdx.z;
  const int tid = threadIdx.x;
  const int w = tid >> 6, lane = tid & 63, lr = lane & 15, lq = lane >> 4;
  const int wm = (w >> 1) << 6, wn = (w & 1) << 5;  // 2x2 waves: 64m x 32n
  __shared__ __align__(16) u16 As[128][72];
  __shared__ __align__(16) u16 Bs[64][72];
  u16* Ts = &As[0][0];  // epilogue staging tile [128][72] (aliases As)
  const u16 *Ag, *Bg;
  int m0, n0, mode, b;
  if (z < 8) {
    const int which = z >> 2;
    b = z & 3;
    Ag = xt + (size_t)b * (T_ * (size_t)C_);
    m0 = blockIdx.x << 7;  // t: 8 tiles
    Bg = which ? wkb : wqb;
    n0 = blockIdx.y << 6;  // o: 8 tiles
    mode = which;          // 0 = Q, 1 = K
  } else {
    b = z - 8;
    const int ti = (blockIdx.y << 3) | blockIdx.x;  // [0,64)
    Ag = wvb;
    m0 = (ti >> 4) << 7;  // o: 4 tiles
    Bg = xt + (size_t)b * (T_ * (size_t)C_);
    n0 = (ti & 15) << 6;  // t: 16 tiles
    mode = 2;
  }
  u16x8 rA0[4], rB0[2], rA1[4], rB1[2];
#define LOADQ(RA, RB, K)                                                  \
  {                                                                       \
    _Pragma("unroll") for (int it = 0; it < 4; ++it) {                    \
      const int e = tid + (it << 8);                                      \
      const int r = e >> 3, c8 = (e & 7) << 3;                            \
      RA[it] = *(const u16x8*)(Ag + (size_t)(m0 + r) * C_ + (K) + c8);    \
    }                                                                     \
    _Pragma("unroll") for (int it = 0; it < 2; ++it) {                    \
      const int e = tid + (it << 8);                                      \
      const int r = e >> 3, c8 = (e & 7) << 3;                            \
      RB[it] = *(const u16x8*)(Bg + (size_t)(n0 + r) * C_ + (K) + c8);    \
    }                                                                     \
  }
#define WRITEQ(RA, RB)                                       \
  {                                                          \
    _Pragma("unroll") for (int it = 0; it < 4; ++it) {       \
      const int e = tid + (it << 8);                         \
      *(u16x8*)&As[e >> 3][(e & 7) << 3] = RA[it];           \
    }                                                        \
    _Pragma("unroll") for (int it = 0; it < 2; ++it) {       \
      const int e = tid + (it << 8);                         \
      *(u16x8*)&Bs[e >> 3][(e & 7) << 3] = RB[it];           \
    }                                                        \
  }
#define MFMAQ()                                                                \
  {                                                                            \
    _Pragma("unroll") for (int kf = 0; kf < 2; ++kf) {                         \
      const int ko = (kf << 5) + (lq << 3);                                    \
      s16x8 a[4], bb[2];                                                       \
      _Pragma("unroll") for (int i = 0; i < 4; ++i) a[i] =                     \
          *(const s16x8*)&As[wm + (i << 4) + lr][ko];                          \
      _Pragma("unroll") for (int j = 0; j < 2; ++j) bb[j] =                    \
          *(const s16x8*)&Bs[wn + (j << 4) + lr][ko];                          \
      _Pragma("unroll") for (int i = 0; i < 4; ++i)                            \
          _Pragma("unroll") for (int j = 0; j < 2; ++j) acc[i][j] =            \
              mfma16(a[i], bb[j], acc[i][j]);                                  \
    }                                                                          \
  }
  f32x4 acc[4][2] = {};
  LOADQ(rA0, rB0, 0);
  LOADQ(rA1, rB1, 64);
  for (int k0 = 0; k0 < C_; k0 += 128) {
    // even K-step (k0)
    if (k0) BARSYNC();  // prev reads consumed (all waves)
    WRITEQ(rA0, rB0);
    if (k0 + 128 < C_) LOADQ(rA0, rB0, k0 + 128);  // 2 phases of cover
    BARSYNC();  // writes committed
    MFMAQ();
    // odd K-step (k0+64)
    BARSYNC();
    WRITEQ(rA1, rB1);
    if (k0 + 192 < C_) LOADQ(rA1, rB1, k0 + 192);
    BARSYNC();
    MFMAQ();
  }
#undef LOADQ
#undef WRITEQ
#undef MFMAQ
  if (mode == 2) {
    // ---- vsum contribution: sum over this tile's 64 t-cols, atomic ----
#pragma unroll
    for (int i = 0; i < 4; ++i)
#pragma unroll
      for (int r = 0; r < 4; ++r) {
        float s = acc[i][0][r] + acc[i][1][r];
        s += __shfl_xor(s, 1, 64);
        s += __shfl_xor(s, 2, 64);
        s += __shfl_xor(s, 4, 64);
        s += __shfl_xor(s, 8, 64);
        if (lr == 0) {
          const int o = m0 + wm + (i << 4) + (lq << 2) + r;
          atomicAdd(&vsum[(((b << 3) | (o >> 6)) << 6) | (o & 63)], s);
        }
      }
  }
  BARSYNC();  // all waves done reading As before Ts overwrite
  // ---- stage output tile [m_local 128][n_local 64] (stride 72) in LDS ----
  const float osc = (mode == 0) ? SCALE_ : 1.0f;
#pragma unroll
  for (int i = 0; i < 4; ++i)
#pragma unroll
    for (int j = 0; j < 2; ++j)
#pragma unroll
      for (int r = 0; r < 4; ++r)
        Ts[(wm + (i << 4) + (lq << 2) + r) * 72 + wn + (j << 4) + lr] =
            f2bf(acc[i][j][r] * osc);
  __syncthreads();
  if (mode == 0) {
    // coalesced Qt store: row = tid>>1, col-half = (tid&1)*32; 4 u16x8 each
    u16* Y = qto + (size_t)b * (T_ * (size_t)C_);
    const int row = tid >> 1, ch32 = (tid & 1) << 5;
    u16* dst = Y + (size_t)(m0 + row) * C_ + n0 + ch32;
    const u16* src = &Ts[row * 72 + ch32];
#pragma unroll
    for (int u = 0; u < 4; ++u)
      *(u16x8*)(dst + (u << 3)) = *(const u16x8*)(src + (u << 3));
    return;
  }
  const int ch = tid >> 4, part = tid & 15;  // 16 chunks x 16 threads
  if (mode == 1) {
    // chunk = (t32l[4], half[2], fl[2]); lanek = u*16+part -> coalesced
    const int t32l = ch >> 2, half = (ch >> 1) & 1, fl = ch & 1;
    const int t32g = (m0 >> 5) + t32l, fg = (n0 >> 5) + fl;
    u16* dst =
        ks + (((((size_t)((b << 5) | t32g) << 1) | half) << 4 | fg) << 9);
#pragma unroll
    for (int u = 0; u < 4; ++u) {
      const int lanek = (u << 4) + part;
      const int quadk = lanek >> 4, lrk = lanek & 15;
      const int rr = ((lrk >> 2) << 3) | (half << 2) | (lrk & 3);
      const u16x8 v =
          *(const u16x8*)&Ts[((t32l << 5) + rr) * 72 + (fl << 5) + (quadk << 3)];
      *(u16x8*)(dst + (lanek << 3)) = v;
    }
  } else {
    // chunk = (gl[2], t32l[2], dj[4]); lanev = u*16+part -> coalesced
    const int gl = ch >> 3, t32l = (ch >> 2) & 1, dj = ch & 3;
    const int gg = (m0 >> 6) + gl, t32g = (n0 >> 5) + t32l;
    u16* dst =
        vs + (((((size_t)((b << 3) | gg) << 5) | t32g) << 2 | dj) << 9);
#pragma unroll
    for (int u = 0; u < 4; ++u) {
      const int lanev = (u << 4) + part;
      const int quadv = lanev >> 4, lrv = lanev & 15;
      const u16x8 v = *(const u16x8*)&Ts[((gl << 6) + (dj << 4) + lrv) * 72 +
                                         (t32l << 5) + (quadv << 3)];
      *(u16x8*)(dst + (lanev << 3)) = v;
    }
  }
}

// ---- FUSED attention: exact R14 structure (best measured: 47.9us, 56
// VGPR, no spill; setprio reverted -- R16 A/B showed it neutral-negative).
// Opart now stored as BF16 (unnormalized partials): halves O-write and
// gemm_proj's dominant 128MB f32 B-read stream. ----
__global__ __launch_bounds__(512, 4) void attn_fused(
    const u16* __restrict__ Qt, const u16* __restrict__ KS,
    const u16* __restrict__ VS, const float* __restrict__ wh,
    u16* __restrict__ Opart, float* __restrict__ lpart,
    float* __restrict__ l2part) {
  const int id = blockIdx.x;
  const int xcd = id & 7;
  const int b = xcd >> 1;
  const int hi = id >> 3;                       // [0,64)
  const int qb = ((xcd & 1) << 5) | (hi & 31);  // [0,64)
  const int tq = hi >> 5;                       // [0,2) t-half
  const int q0 = qb << 4;
  const int tid = threadIdx.x;
  const int w = tid >> 6, lane = tid & 63;
  const int lr = lane & 15, quad = lane >> 4;

  __shared__ __align__(16) u16 Qs[16][522];       // 16704 B
  __shared__ __align__(16) u16 Plds[8][16][136];  // 34816 B
  float* Sbuf = (float*)&Plds[0][0][0];  // epilogue alias (Plds dead by then)

  {  // stage Q tile (16 x 512)
    const u16* Qb = Qt + ((size_t)b * T_ + q0) * C_;
    for (int i = tid; i < 1024; i += 512) {
      const int r = i >> 6, c8 = i & 63;
      *(u16x8*)&Qs[r][c8 << 3] = *(const u16x8*)(Qb + (size_t)r * C_ + (c8 << 3));
    }
  }

  const u16* __restrict__ Qrow = &Qs[lr][quad << 3];
  const int g = w;  // PV head owned by this wave
  const int win = w >> 1, half = w & 1;  // QK: window pair, K-half
  const u16* __restrict__ Vc =
      VS + (((size_t)((b << 3) | g)) << 16) + (lane << 3);

  float lacc[8] = {}, l2acc[8] = {};
  f32x4 acc[4] = {};

  __syncthreads();

  for (int c = 0; c < 4; ++c) {
    // ---- QK + mix + exp: K loads lane-contiguous from KS ----
    const int t32k = (tq << 4) + (c << 2) + win;
    const u16* __restrict__ Kc =
        KS + (((size_t)((((b << 5) | t32k) << 1) | half)) << 13) + (lane << 3);
    f32x4 m[8] = {};
#pragma unroll 4
    for (int h = 0; h < 8; ++h) {
      f32x4 a0 = {0.f, 0.f, 0.f, 0.f};
      const s16x8 qf0 = *(const s16x8*)(Qrow + (h << 6));
      const s16x8 k0 = *(const s16x8*)(Kc + (h << 10));
      a0 = mfma16(k0, qf0, a0);
      const s16x8 qf1 = *(const s16x8*)(Qrow + (h << 6) + 32);
      const s16x8 k1 = *(const s16x8*)(Kc + (h << 10) + 512);
      a0 = mfma16(k1, qf1, a0);
#pragma unroll
      for (int gg = 0; gg < 8; ++gg) {
        const float wgh = wh[(gg << 3) + h];  // uniform -> SGPR
        m[gg] += a0 * wgh;
      }
    }
    // lane's t slots: win*32 + quad*8 + half*4 + {0..3}; q = lr
#pragma unroll
    for (int gg = 0; gg < 8; ++gg) {
      f32x4 e0;
#pragma unroll
      for (int k = 0; k < 4; ++k) e0[k] = __expf(m[gg][k]);
      u16x4 o;
#pragma unroll
      for (int k = 0; k < 4; ++k) o[k] = f2bf(e0[k]);
      *(u16x4*)&Plds[gg][lr][(win << 5) + (quad << 3) + (half << 2)] = o;
      lacc[gg] += e0[0] + e0[1] + e0[2] + e0[3];
      l2acc[gg] += e0[0] * e0[0] + e0[1] * e0[1] + e0[2] * e0[2] + e0[3] * e0[3];
    }
    __syncthreads();  // P ready
    // ---- PV: V loads lane-contiguous from VS ----
#pragma unroll
    for (int tw = 0; tw < 4; ++tw) {
      const int t32v = (tq << 4) + (c << 2) + tw;
      const s16x8 pa = *(const s16x8*)&Plds[g][lr][(tw << 5) + (quad << 3)];
#pragma unroll
      for (int dj = 0; dj < 4; ++dj) {
        const s16x8 vb =
            *(const s16x8*)(Vc + ((size_t)t32v << 11) + (dj << 9));
        acc[dj] = mfma16(pa, vb, acc[dj]);
      }
    }
    __syncthreads();  // P consumed, safe to overwrite next chunk
  }

  // ---- write bf16 partial O (normalization happens in gemm_proj) ----
  const int bg = (b << 3) + g;
  const size_t obase = ((((size_t)(tq << 5) + bg) << 10) + q0) * 64;
#pragma unroll
  for (int dj = 0; dj < 4; ++dj) {
    const int d = (dj << 4) + lr;
#pragma unroll
    for (int r = 0; r < 4; ++r) {
      const int q = (quad << 2) + r;
      Opart[obase + (size_t)q * 64 + d] = f2bf(acc[dj][r]);
    }
  }

  // ---- epilogue: l/l2 reduce (buffers alias Plds), write partials ----
  float* lbuf = Sbuf;          // [8w][8g][16q]  4 KB
  float* l2buf = Sbuf + 1024;  // [8w][8g][16q]  4 KB
#pragma unroll
  for (int gg = 0; gg < 8; ++gg) {
    float l = lacc[gg];
    l += __shfl_xor(l, 16, 64);
    l += __shfl_xor(l, 32, 64);
    float l2 = l2acc[gg];
    l2 += __shfl_xor(l2, 16, 64);
    l2 += __shfl_xor(l2, 32, 64);
    if (quad == 0) {
      lbuf[(w << 7) + (gg << 4) + lr] = l;
      l2buf[(w << 7) + (gg << 4) + lr] = l2;
    }
  }
  __syncthreads();
  if (lane < 16) {  // wave w reduces its own g
    float l = 0.f, l2 = 0.f;
#pragma unroll
    for (int w2 = 0; w2 < 8; ++w2) {
      l += lbuf[(w2 << 7) + (g << 4) + lr];
      l2 += l2buf[(w2 << 7) + (g << 4) + lr];
    }
    const size_t li = (((size_t)(tq << 5) + bg) << 10) + q0 + lr;
    lpart[li] = l;
    l2part[li] = l2;
  }
}

// ------- y = al*(Onorm @ Wp^T) + bias2, 64x64 tiles, 512 blocks.
// combine_o folded in; Opart now BF16 -> B-read stream halved. ----
__global__ __launch_bounds__(256) void gemm_proj(
    const u16* __restrict__ Opart, const u16* __restrict__ wpb,
    const float* __restrict__ lpart, const float* __restrict__ l2part,
    const float* __restrict__ gamma, const float* __restrict__ beta,
    const float* __restrict__ ws, const float* __restrict__ bp,
    const float* __restrict__ vsum, float* __restrict__ y) {
  const int b = blockIdx.z;
  const int m0 = blockIdx.y << 6;  // o: 8 tiles
  const int n0 = blockIdx.x << 6;  // t: 16 tiles
  const int gidx = blockIdx.x >> 1;
  const int bg = (b << 3) + gidx;
  __shared__ __align__(16) u16 As[64][72];
  __shared__ __align__(16) u16 Bs[64][72];
  __shared__ float red[4];
  __shared__ float albc[2];
  __shared__ float b2s[64];
  __shared__ float linvS[512];
  const int tid = threadIdx.x;
  const int w = tid >> 6, lane = tid & 63, lr = lane & 15, lq = lane >> 4;
  const int mw = (w >> 1) << 5, nw = (w & 1) << 5;
  u16x8 rA[2];
  u16x8 rB16[2][2];  // [it][tq]
#define LOADP(K)                                                            \
  {                                                                         \
    _Pragma("unroll") for (int it = 0; it < 2; ++it) {                      \
      const int e = tid + (it << 8);                                        \
      const int r = e >> 3, c8 = (e & 7) << 3;                              \
      rA[it] = *(const u16x8*)(wpb + (size_t)(m0 + r) * C_ + (K) + c8);     \
      const int q = (((n0 + r) & 127) << 3) + ((K) >> 6);                   \
      _Pragma("unroll") for (int tq = 0; tq < 2; ++tq) {                    \
        rB16[it][tq] = *(const u16x8*)(Opart +                              \
            ((((size_t)((tq << 5) + bg)) << 10) + q) * 64 + c8);            \
      }                                                                     \
    }                                                                       \
  }
  LOADP(0);  // in flight under the prologue stats
  // ---- prologue: ssq reduce over full 1024 q (from partials) ----
  {
    const size_t p0 = ((size_t)bg) << 10, p1 = ((size_t)(32 + bg)) << 10;
    const f32x4 la = *(const f32x4*)(lpart + p0 + (tid << 2));
    const f32x4 lb = *(const f32x4*)(lpart + p1 + (tid << 2));
    const f32x4 l2a = *(const f32x4*)(l2part + p0 + (tid << 2));
    const f32x4 l2b = *(const f32x4*)(l2part + p1 + (tid << 2));
    float ssq = 0.f;
#pragma unroll
    for (int k = 0; k < 4; ++k) {
      const float l = la[k] + lb[k];
      ssq += (l2a[k] + l2b[k]) / (l * l);
    }
#pragma unroll
    for (int off = 32; off; off >>= 1) ssq += __shfl_xor(ssq, off, 64);
    if (lane == 0) red[w] = ssq;
    // linv for this block's 512-q window (qb0 = (n0&127)*8 = 0 or 512)
    const int qb0 = (n0 & 127) << 3;
#pragma unroll
    for (int j = 0; j < 2; ++j) {
      const int qq = (tid << 1) + j;
      const float l = lpart[p0 + qb0 + qq] + lpart[p1 + qb0 + qq];
      linvS[qq] = 1.f / l;
    }
  }
  __syncthreads();
  if (tid == 0) {
    const float s = red[0] + red[1] + red[2] + red[3];
    const float mean = 0.0009765625f;
    const float var = s * (1.f / 1048576.f) - mean * mean;
    const float al = gamma[gidx] * rsqrtf(var + EPS_);
    albc[0] = al;
    albc[1] = beta[gidx] - al * mean;
  }
  __syncthreads();
  if (tid < 64) {
    const int o = m0 + tid;
    const float* wr = ws + (o << 6);
    const float* vsr = vsum + (bg << 6);
    float acc = 0.f;
#pragma unroll
    for (int d = 0; d < 64; d += 4) {
      const float4 vv4 = *(const float4*)(vsr + d);
      const float4 ws4 = *(const float4*)(wr + d);
      acc += ws4.x * vv4.x + ws4.y * vv4.y + ws4.z * vv4.z + ws4.w * vv4.w;
    }
    b2s[tid] = bp[o] + albc[1] * acc;
  }
  f32x4 acc[2][2] = {};
  for (int k0 = 0; k0 < C_; k0 += 64) {
    if (k0) BARSYNC();
    __syncthreads();  // k0==0: b2s/linvS visible; k0>0: harmless extra sync
#pragma unroll
    for (int it = 0; it < 2; ++it) {
      const int e = tid + (it << 8);
      const int r = e >> 3, c8 = (e & 7) << 3;
      *(u16x8*)&As[r][c8] = rA[it];
      const float li = linvS[(r << 3) + (k0 >> 6)];
      u16x8 o;
#pragma unroll
      for (int k = 0; k < 8; ++k)
        o[k] = f2bf((b2f(rB16[it][0][k]) + b2f(rB16[it][1][k])) * li);
      *(u16x8*)&Bs[r][c8] = o;
    }
    if (k0 < C_ - 64) LOADP(k0 + 64);  // in flight across MFMA phase
    BARSYNC();
#pragma unroll
    for (int kf = 0; kf < 2; ++kf) {
      const int ko = (kf << 5) + (lq << 3);
      s16x8 a[2], bb[2];
#pragma unroll
      for (int i = 0; i < 2; ++i) a[i] = *(const s16x8*)&As[mw + (i << 4) + lr][ko];
#pragma unroll
      for (int j = 0; j < 2; ++j) bb[j] = *(const s16x8*)&Bs[nw + (j << 4) + lr][ko];
#pragma unroll
      for (int i = 0; i < 2; ++i)
#pragma unroll
        for (int j = 0; j < 2; ++j) acc[i][j] = mfma16(a[i], bb[j], acc[i][j]);
    }
  }
#undef LOADP
  const float al = albc[0];
#pragma unroll
  for (int i = 0; i < 2; ++i) {
    const int row = mw + (i << 4) + (lq << 2);
#pragma unroll
    for (int j = 0; j < 2; ++j) {
      const int col = nw + (j << 4) + lr;
#pragma unroll
      for (int r = 0; r < 4; ++r)
        y[(size_t)b * (C_ * (size_t)T_) + (size_t)(m0 + row + r) * T_ + n0 + col] =
            acc[i][j][r] * al + b2s[row + r];
    }
  }
}

extern "C" void kernel_launch(void* const* d_in, const int* in_sizes, int n_in,
                              void* d_out, int out_size, void* d_ws,
                              size_t ws_size, hipStream_t stream) {
  const float* x = (const float*)d_in[0];
  const float* wq = (const float*)d_in[1];
  const float* wk = (const float*)d_in[2];
  const float* wv = (const float*)d_in[3];
  const float* wh = (const float*)d_in[4];
  const float* gm = (const float*)d_in[5];
  const float* bt = (const float*)d_in[6];
  const float* wp = (const float*)d_in[7];
  const float* bp = (const float*)d_in[8];
  float* y = (float*)d_out;
  char* wsb = (char*)d_ws;

  u16* Qt = (u16*)(wsb + QT_OFF);
  u16* KS = (u16*)(wsb + KS_OFF);
  u16* VS = (u16*)(wsb + VS_OFF);
  u16* Xt = (u16*)(wsb + XT_OFF);
  float* vsum = (float*)(wsb + VSUM_OFF);
  u16* Wb = (u16*)(wsb + WB_OFF);
  u16* WQb = Wb;
  u16* WKb = Wb + 262144;
  u16* WVb = Wb + 524288;
  u16* WPb = Wb + 786432;
  float* lpart = (float*)(wsb + LP_OFF);
  float* l2part = (float*)(wsb + L2P_OFF);
  float* ws = (float*)(wsb + WS_OFF);
  u16* Opart = (u16*)(wsb + OP_OFF);

  prep_k<<<dim3(1152), 256, 0, stream>>>(x, wq, wk, wv, wp, Wb, ws, vsum, Xt);
  gemm_qkv<<<dim3(8, 8, 12), 256, 0, stream>>>(Xt, WQb, WKb, WVb, Qt, KS, VS,
                                               vsum);
  attn_fused<<<dim3(512), 512, 0, stream>>>(Qt, KS, VS, wh, Opart, lpart,
                                            l2part);
  gemm_proj<<<dim3(16, 8, 4), 256, 0, stream>>>(Opart, WPb, lpart, l2part, gm,
                                                bt, ws, bp, vsum, y);
}